// Round 2
// baseline (1095.102 us; speedup 1.0000x reference)
//
#include <hip/hip_runtime.h>

#define N_NODES 65536
#define G_GRID  32768
#define E_EDGES 600000
#define HD      128

typedef __attribute__((ext_vector_type(8))) short bf8;
typedef __attribute__((ext_vector_type(4))) float f32x4;

__device__ __forceinline__ short f2bf(float f){
  union { float f; unsigned u; } v; v.f = f;
  unsigned r = v.u + 0x7FFFu + ((v.u >> 16) & 1u);
  return (short)(r >> 16);
}

__device__ __forceinline__ bf8 load_pack8(const float* p, float scale){
  float4 u0 = *(const float4*)p;
  float4 u1 = *(const float4*)(p + 4);
  bf8 r;
  r[0]=f2bf(u0.x*scale); r[1]=f2bf(u0.y*scale); r[2]=f2bf(u0.z*scale); r[3]=f2bf(u0.w*scale);
  r[4]=f2bf(u1.x*scale); r[5]=f2bf(u1.y*scale); r[6]=f2bf(u1.z*scale); r[7]=f2bf(u1.w*scale);
  return r;
}

// Transpose + bf16-quantize weights: dst holds Wt[n][k] per matrix.
// Ranges (elements): nm_w1t [0,16384) K=128, nm_w2t [16384,32768), em_w2t [32768,49152),
// mm_w1t [49152,81920) K=256, mm_w2t [81920,98304).
__global__ void prep_w_k(const float* __restrict__ nmw1, const float* __restrict__ nmw2,
                         const float* __restrict__ emw2, const float* __restrict__ mmw1,
                         const float* __restrict__ mmw2, short* __restrict__ dst)
{
  int i = blockIdx.x*256 + threadIdx.x;  // < 98304
  const float* src; int local; bool k256 = false;
  if      (i < 16384){ src = nmw1; local = i; }
  else if (i < 32768){ src = nmw2; local = i - 16384; }
  else if (i < 49152){ src = emw2; local = i - 32768; }
  else if (i < 81920){ src = mmw1; local = i - 49152; k256 = true; }
  else               { src = mmw2; local = i - 81920; }
  int n, k;
  if (k256){ n = local >> 8; k = local & 255; }
  else     { n = local >> 7; k = local & 127; }
  dst[i] = f2bf(src[k*HD + n]);
}

// Node MLP: nf = silu(X@W1+b1)@W2+b2, output bf16 [N,128].
// Block = 256 threads = 4 waves; each wave owns a 16-row tile; block covers 64 rows.
__global__ void node_mlp_k(const float* __restrict__ X,
                           const short* __restrict__ w1t, const float* __restrict__ b1,
                           const short* __restrict__ w2t, const float* __restrict__ b2,
                           short* __restrict__ nf)
{
  __shared__ short hid[64][136];   // +8 pad: row stride 272B -> 2-way conflicts only
  const int t = threadIdx.x;
  const int wave = t >> 6, lane = t & 63, l15 = lane & 15, q = lane >> 4;
  const int rw = blockIdx.x*64 + wave*16;

  // A fragments (fp32 -> bf16), kept in regs for both col loops
  bf8 a[4];
  const float* xr = X + (size_t)(rw + l15)*HD;
  #pragma unroll
  for (int kt=0; kt<4; kt++) a[kt] = load_pack8(xr + kt*32 + q*8, 1.0f);

  #pragma unroll
  for (int ct=0; ct<8; ct++){
    f32x4 acc = {0.f,0.f,0.f,0.f};
    #pragma unroll
    for (int kt=0; kt<4; kt++){
      bf8 b = *(const bf8*)(w1t + (ct*16 + l15)*HD + kt*32 + q*8);
      acc = __builtin_amdgcn_mfma_f32_16x16x32_bf16(a[kt], b, acc, 0, 0, 0);
    }
    float bias = b1[ct*16 + l15];
    #pragma unroll
    for (int r=0;r<4;r++){
      float v = acc[r] + bias;
      v = v / (1.f + __expf(-v));               // silu
      hid[wave*16 + q*4 + r][ct*16 + l15] = f2bf(v);
    }
  }
  __syncthreads();

  bf8 a2[4];
  #pragma unroll
  for (int kt=0;kt<4;kt++) a2[kt] = *(const bf8*)&hid[wave*16 + l15][kt*32 + q*8];
  #pragma unroll
  for (int ct=0; ct<8; ct++){
    f32x4 acc = {0.f,0.f,0.f,0.f};
    #pragma unroll
    for (int kt=0;kt<4;kt++){
      bf8 b = *(const bf8*)(w2t + (ct*16 + l15)*HD + kt*32 + q*8);
      acc = __builtin_amdgcn_mfma_f32_16x16x32_bf16(a2[kt], b, acc, 0, 0, 0);
    }
    float bias = b2[ct*16 + l15];
    #pragma unroll
    for (int r=0;r<4;r++)
      nf[(size_t)(rw + q*4 + r)*HD + ct*16 + l15] = f2bf(acc[r] + bias);
  }
}

// Fused edge-feature MLP + message MLP + atomic scatter. 64 edges per block.
__global__ void edge_msg_k(const int* __restrict__ eidx,
                           const float* __restrict__ npos, const float* __restrict__ gpos,
                           const float* __restrict__ ew1, const float* __restrict__ eb1,
                           const short* __restrict__ ew2t, const float* __restrict__ eb2,
                           const short* __restrict__ mw1t, const float* __restrict__ mb1,
                           const short* __restrict__ mw2t, const float* __restrict__ mb2,
                           const short* __restrict__ nf,
                           float* __restrict__ agg, float* __restrict__ cnt)
{
  __shared__ float attr[64][8];
  __shared__ int srcs[64], tgts[64];
  __shared__ short hm[64][136];    // edge hidden1, later reused as msg hidden (wave-local reuse)
  __shared__ short efs[64][136];
  __shared__ short nfs[64][136];

  const int t = threadIdx.x;
  const int e0 = blockIdx.x*64;

  if (t < 64){
    int e = e0 + t;
    int s = eidx[e];
    int g = eidx[E_EDGES + e];
    srcs[t] = s; tgts[t] = g;
    attr[t][0] = npos[s*3+0]; attr[t][1] = npos[s*3+1]; attr[t][2] = npos[s*3+2];
    attr[t][3] = gpos[g*3+0]; attr[t][4] = gpos[g*3+1]; attr[t][5] = gpos[g*3+2];
    atomicAdd(&cnt[g], 1.0f);
  }
  __syncthreads();

  // gather nf[src] (bf16) -> nfs : thread covers 64B of one edge row
  {
    int e = t >> 2, part = t & 3;
    const short* sp = nf + (size_t)srcs[e]*HD + part*32;
    #pragma unroll
    for (int i=0;i<4;i++)
      *(int4*)&nfs[e][part*32 + i*8] = *(const int4*)(sp + i*8);
  }
  // edge hidden1 (K=6, fp32 exact): thread -> edge t&63, 32 cols
  {
    int e = t & 63, nb = (t >> 6)*32;
    float a0=attr[e][0], a1=attr[e][1], a2=attr[e][2],
          a3=attr[e][3], a4=attr[e][4], a5=attr[e][5];
    #pragma unroll 8
    for (int j=0;j<32;j++){
      int n = nb + j;
      float v = eb1[n] + a0*ew1[n] + a1*ew1[HD+n] + a2*ew1[2*HD+n]
              + a3*ew1[3*HD+n] + a4*ew1[4*HD+n] + a5*ew1[5*HD+n];
      v = v / (1.f + __expf(-v));
      hm[e][n] = f2bf(v);
    }
  }
  __syncthreads();

  const int wave = t >> 6, lane = t & 63, l15 = lane & 15, q = lane >> 4;
  const int rl = wave*16;

  // ef = hm @ em_w2t + eb2  -> efs
  bf8 a[4];
  #pragma unroll
  for (int kt=0;kt<4;kt++) a[kt] = *(const bf8*)&hm[rl + l15][kt*32 + q*8];
  #pragma unroll
  for (int ct=0; ct<8; ct++){
    f32x4 acc = {0.f,0.f,0.f,0.f};
    #pragma unroll
    for (int kt=0;kt<4;kt++){
      bf8 b = *(const bf8*)(ew2t + (ct*16 + l15)*HD + kt*32 + q*8);
      acc = __builtin_amdgcn_mfma_f32_16x16x32_bf16(a[kt], b, acc, 0,0,0);
    }
    float bias = eb2[ct*16 + l15];
    #pragma unroll
    for (int r=0;r<4;r++) efs[rl + q*4 + r][ct*16 + l15] = f2bf(acc[r] + bias);
  }

  // msg hidden = silu(nfs@W1[0:128] + efs@W1[128:256] + mb1) -> hm (reuse, wave-local rows)
  bf8 an[4], ae[4];
  #pragma unroll
  for (int kt=0;kt<4;kt++){
    an[kt] = *(const bf8*)&nfs[rl + l15][kt*32 + q*8];
    ae[kt] = *(const bf8*)&efs[rl + l15][kt*32 + q*8];
  }
  #pragma unroll
  for (int ct=0; ct<8; ct++){
    f32x4 acc = {0.f,0.f,0.f,0.f};
    #pragma unroll
    for (int kt=0;kt<4;kt++){
      bf8 b = *(const bf8*)(mw1t + (ct*16 + l15)*256 + kt*32 + q*8);
      acc = __builtin_amdgcn_mfma_f32_16x16x32_bf16(an[kt], b, acc, 0,0,0);
    }
    #pragma unroll
    for (int kt=0;kt<4;kt++){
      bf8 b = *(const bf8*)(mw1t + (ct*16 + l15)*256 + 128 + kt*32 + q*8);
      acc = __builtin_amdgcn_mfma_f32_16x16x32_bf16(ae[kt], b, acc, 0,0,0);
    }
    float bias = mb1[ct*16 + l15];
    #pragma unroll
    for (int r=0;r<4;r++){
      float v = acc[r] + bias;
      v = v / (1.f + __expf(-v));
      hm[rl + q*4 + r][ct*16 + l15] = f2bf(v);
    }
  }

  // msg = hm @ mm_w2t + mb2 -> atomicAdd into agg[tgt]
  bf8 am[4];
  #pragma unroll
  for (int kt=0;kt<4;kt++) am[kt] = *(const bf8*)&hm[rl + l15][kt*32 + q*8];
  int tg[4];
  #pragma unroll
  for (int r=0;r<4;r++) tg[r] = tgts[rl + q*4 + r];
  #pragma unroll
  for (int ct=0; ct<8; ct++){
    f32x4 acc = {0.f,0.f,0.f,0.f};
    #pragma unroll
    for (int kt=0;kt<4;kt++){
      bf8 b = *(const bf8*)(mw2t + (ct*16 + l15)*HD + kt*32 + q*8);
      acc = __builtin_amdgcn_mfma_f32_16x16x32_bf16(am[kt], b, acc, 0,0,0);
    }
    float bias = mb2[ct*16 + l15];
    int col = ct*16 + l15;
    #pragma unroll
    for (int r=0;r<4;r++)
      atomicAdd(&agg[(size_t)tg[r]*HD + col], acc[r] + bias);
  }
}

// Update MLP in full fp32 (accuracy anchor): out = silu(x@W1+b1)@W2+b2, x = agg/max(cnt,1)
__global__ void update_mlp_k(const float* __restrict__ agg, const float* __restrict__ cnt,
                             const float* __restrict__ w1, const float* __restrict__ b1,
                             const float* __restrict__ w2, const float* __restrict__ b2,
                             float* __restrict__ out)
{
  __shared__ float xs[32][129];
  __shared__ float hs[32][129];
  const int t = threadIdx.x;
  const int rb = blockIdx.x*32;
  {
    int e = t >> 3, c0 = (t & 7)*16;
    float c = cnt[rb + e];
    float rcp = 1.0f / fmaxf(c, 1.0f);
    const float* p = agg + (size_t)(rb + e)*HD + c0;
    #pragma unroll
    for (int i=0;i<16;i++) xs[e][c0+i] = p[i]*rcp;
  }
  __syncthreads();
  int e = t >> 3, n0 = (t & 7)*16;
  float acc[16];
  #pragma unroll
  for (int j=0;j<16;j++) acc[j] = b1[n0+j];
  for (int k=0;k<HD;k++){
    float x = xs[e][k];
    const float* wr = w1 + k*HD + n0;
    #pragma unroll
    for (int j=0;j<16;j++) acc[j] += x * wr[j];
  }
  #pragma unroll
  for (int j=0;j<16;j++){
    float v = acc[j];
    hs[e][n0+j] = v / (1.f + expf(-v));
  }
  __syncthreads();
  #pragma unroll
  for (int j=0;j<16;j++) acc[j] = b2[n0+j];
  for (int k=0;k<HD;k++){
    float x = hs[e][k];
    const float* wr = w2 + k*HD + n0;
    #pragma unroll
    for (int j=0;j<16;j++) acc[j] += x * wr[j];
  }
  float* op = out + (size_t)(rb + e)*HD + n0;
  #pragma unroll
  for (int j=0;j<16;j++) op[j] = acc[j];
}

extern "C" void kernel_launch(void* const* d_in, const int* in_sizes, int n_in,
                              void* d_out, int out_size, void* d_ws, size_t ws_size,
                              hipStream_t stream)
{
  const float* node_features = (const float*)d_in[0];
  const float* node_pos      = (const float*)d_in[1];
  const float* grid_pos      = (const float*)d_in[2];
  const int*   edge_index    = (const int*)d_in[3];
  const float* nm_w1 = (const float*)d_in[4];
  const float* nm_b1 = (const float*)d_in[5];
  const float* nm_w2 = (const float*)d_in[6];
  const float* nm_b2 = (const float*)d_in[7];
  const float* em_w1 = (const float*)d_in[8];
  const float* em_b1 = (const float*)d_in[9];
  const float* em_w2 = (const float*)d_in[10];
  const float* em_b2 = (const float*)d_in[11];
  const float* mm_w1 = (const float*)d_in[12];
  const float* mm_b1 = (const float*)d_in[13];
  const float* mm_w2 = (const float*)d_in[14];
  const float* mm_b2 = (const float*)d_in[15];
  const float* um_w1 = (const float*)d_in[16];
  const float* um_b1 = (const float*)d_in[17];
  const float* um_w2 = (const float*)d_in[18];
  const float* um_b2 = (const float*)d_in[19];
  float* out = (float*)d_out;

  char* ws = (char*)d_ws;
  short* nf  = (short*)ws;                          // 16 MB   bf16 [N,128]
  float* agg = (float*)(ws + (size_t)16777216);     // 16 MB   f32  [G,128]
  float* cnt = (float*)(ws + (size_t)33554432);     // 128 KB  f32  [G]
  short* wts = (short*)(ws + (size_t)33685504);     // ~192 KB bf16 transposed weights
  short* nmw1t = wts;
  short* nmw2t = wts + 16384;
  short* emw2t = wts + 32768;
  short* mmw1t = wts + 49152;
  short* mmw2t = wts + 81920;

  // zero agg + cnt (contiguous)
  (void)hipMemsetAsync(ws + (size_t)16777216, 0, (size_t)16777216 + 131072, stream);

  prep_w_k<<<384, 256, 0, stream>>>(nm_w1, nm_w2, em_w2, mm_w1, mm_w2, wts);
  node_mlp_k<<<N_NODES/64, 256, 0, stream>>>(node_features, nmw1t, nm_b1, nmw2t, nm_b2, nf);
  edge_msg_k<<<E_EDGES/64, 256, 0, stream>>>(edge_index, node_pos, grid_pos,
      em_w1, em_b1, emw2t, em_b2, mmw1t, mm_b1, mmw2t, mm_b2, nf, agg, cnt);
  update_mlp_k<<<G_GRID/32, 256, 0, stream>>>(agg, cnt, um_w1, um_b1, um_w2, um_b2, out);
}

// Round 3
// 989.965 us; speedup vs baseline: 1.1062x; 1.1062x over previous
//
#include <hip/hip_runtime.h>

#define N_NODES 65536
#define G_GRID  32768
#define E_EDGES 600000
#define HD      128

typedef __attribute__((ext_vector_type(8))) short bf8;
typedef __attribute__((ext_vector_type(4))) float f32x4;

__device__ __forceinline__ short f2bf(float f){
  union { float f; unsigned u; } v; v.f = f;
  unsigned r = v.u + 0x7FFFu + ((v.u >> 16) & 1u);
  return (short)(r >> 16);
}

__device__ __forceinline__ bf8 load_pack8(const float* p, float scale){
  float4 u0 = *(const float4*)p;
  float4 u1 = *(const float4*)(p + 4);
  bf8 r;
  r[0]=f2bf(u0.x*scale); r[1]=f2bf(u0.y*scale); r[2]=f2bf(u0.z*scale); r[3]=f2bf(u0.w*scale);
  r[4]=f2bf(u1.x*scale); r[5]=f2bf(u1.y*scale); r[6]=f2bf(u1.z*scale); r[7]=f2bf(u1.w*scale);
  return r;
}

// Transpose + bf16-quantize weights: dst holds Wt[n][k] per matrix.
__global__ void prep_w_k(const float* __restrict__ nmw1, const float* __restrict__ nmw2,
                         const float* __restrict__ emw2, const float* __restrict__ mmw1,
                         const float* __restrict__ mmw2, short* __restrict__ dst)
{
  int i = blockIdx.x*256 + threadIdx.x;  // < 98304
  const float* src; int local; bool k256 = false;
  if      (i < 16384){ src = nmw1; local = i; }
  else if (i < 32768){ src = nmw2; local = i - 16384; }
  else if (i < 49152){ src = emw2; local = i - 32768; }
  else if (i < 81920){ src = mmw1; local = i - 49152; k256 = true; }
  else               { src = mmw2; local = i - 81920; }
  int n, k;
  if (k256){ n = local >> 8; k = local & 255; }
  else     { n = local >> 7; k = local & 127; }
  dst[i] = f2bf(src[k*HD + n]);
}

// Node MLP: nf = silu(X@W1+b1)@W2+b2, output bf16 [N,128].
__global__ void node_mlp_k(const float* __restrict__ X,
                           const short* __restrict__ w1t, const float* __restrict__ b1,
                           const short* __restrict__ w2t, const float* __restrict__ b2,
                           short* __restrict__ nf)
{
  __shared__ short hid[64][136];
  const int t = threadIdx.x;
  const int wave = t >> 6, lane = t & 63, l15 = lane & 15, q = lane >> 4;
  const int rw = blockIdx.x*64 + wave*16;

  bf8 a[4];
  const float* xr = X + (size_t)(rw + l15)*HD;
  #pragma unroll
  for (int kt=0; kt<4; kt++) a[kt] = load_pack8(xr + kt*32 + q*8, 1.0f);

  #pragma unroll
  for (int ct=0; ct<8; ct++){
    f32x4 acc = {0.f,0.f,0.f,0.f};
    #pragma unroll
    for (int kt=0; kt<4; kt++){
      bf8 b = *(const bf8*)(w1t + (ct*16 + l15)*HD + kt*32 + q*8);
      acc = __builtin_amdgcn_mfma_f32_16x16x32_bf16(a[kt], b, acc, 0, 0, 0);
    }
    float bias = b1[ct*16 + l15];
    #pragma unroll
    for (int r=0;r<4;r++){
      float v = acc[r] + bias;
      v = v / (1.f + __expf(-v));
      hid[wave*16 + q*4 + r][ct*16 + l15] = f2bf(v);
    }
  }
  __syncthreads();

  bf8 a2[4];
  #pragma unroll
  for (int kt=0;kt<4;kt++) a2[kt] = *(const bf8*)&hid[wave*16 + l15][kt*32 + q*8];
  #pragma unroll
  for (int ct=0; ct<8; ct++){
    f32x4 acc = {0.f,0.f,0.f,0.f};
    #pragma unroll
    for (int kt=0;kt<4;kt++){
      bf8 b = *(const bf8*)(w2t + (ct*16 + l15)*HD + kt*32 + q*8);
      acc = __builtin_amdgcn_mfma_f32_16x16x32_bf16(a2[kt], b, acc, 0, 0, 0);
    }
    float bias = b2[ct*16 + l15];
    #pragma unroll
    for (int r=0;r<4;r++)
      nf[(size_t)(rw + q*4 + r)*HD + ct*16 + l15] = f2bf(acc[r] + bias);
  }
}

// Fused edge-feature MLP + message MLP + atomic scatter. 64 edges per block.
// nf[src] A-fragments gathered DIRECTLY from global (no LDS staging) ->
// LDS 37.4KB -> 4 blocks/CU (16 waves) vs 2 blocks at 54.8KB.
__global__ void __launch_bounds__(256, 4)
edge_msg_k(const int* __restrict__ eidx,
           const float* __restrict__ npos, const float* __restrict__ gpos,
           const float* __restrict__ ew1, const float* __restrict__ eb1,
           const short* __restrict__ ew2t, const float* __restrict__ eb2,
           const short* __restrict__ mw1t, const float* __restrict__ mb1,
           const short* __restrict__ mw2t, const float* __restrict__ mb2,
           const short* __restrict__ nf,
           float* __restrict__ agg, float* __restrict__ cnt)
{
  __shared__ float attr[64][8];
  __shared__ int srcs[64], tgts[64];
  __shared__ short hm[64][136];    // edge hidden1, later reused as msg hidden (wave-local rows)
  __shared__ short efs[64][136];

  const int t = threadIdx.x;
  const int e0 = blockIdx.x*64;
  const int wave = t >> 6, lane = t & 63, l15 = lane & 15, q = lane >> 4;
  const int rl = wave*16;

  if (t < 64){
    int e = e0 + t;
    int s = eidx[e];
    int g = eidx[E_EDGES + e];
    srcs[t] = s; tgts[t] = g;
    attr[t][0] = npos[s*3+0]; attr[t][1] = npos[s*3+1]; attr[t][2] = npos[s*3+2];
    attr[t][3] = gpos[g*3+0]; attr[t][4] = gpos[g*3+1]; attr[t][5] = gpos[g*3+2];
    atomicAdd(&cnt[g], 1.0f);
  }
  __syncthreads();

  // Issue nf[src] A-fragment gather EARLY (overlaps edge-hidden1 compute)
  bf8 an[4];
  {
    const short* nr = nf + (size_t)srcs[rl + l15]*HD + q*8;
    #pragma unroll
    for (int kt=0;kt<4;kt++) an[kt] = *(const bf8*)(nr + kt*32);
  }

  // edge hidden1 (K=6, fp32 exact): thread -> edge t&63, 32 cols
  {
    int e = t & 63, nb = (t >> 6)*32;
    float a0=attr[e][0], a1=attr[e][1], a2=attr[e][2],
          a3=attr[e][3], a4=attr[e][4], a5=attr[e][5];
    #pragma unroll 8
    for (int j=0;j<32;j++){
      int n = nb + j;
      float v = eb1[n] + a0*ew1[n] + a1*ew1[HD+n] + a2*ew1[2*HD+n]
              + a3*ew1[3*HD+n] + a4*ew1[4*HD+n] + a5*ew1[5*HD+n];
      v = v / (1.f + __expf(-v));
      hm[e][n] = f2bf(v);
    }
  }
  __syncthreads();

  // ef = hm @ em_w2t + eb2  -> efs
  bf8 a[4];
  #pragma unroll
  for (int kt=0;kt<4;kt++) a[kt] = *(const bf8*)&hm[rl + l15][kt*32 + q*8];
  #pragma unroll
  for (int ct=0; ct<8; ct++){
    f32x4 acc = {0.f,0.f,0.f,0.f};
    #pragma unroll
    for (int kt=0;kt<4;kt++){
      bf8 b = *(const bf8*)(ew2t + (ct*16 + l15)*HD + kt*32 + q*8);
      acc = __builtin_amdgcn_mfma_f32_16x16x32_bf16(a[kt], b, acc, 0,0,0);
    }
    float bias = eb2[ct*16 + l15];
    #pragma unroll
    for (int r=0;r<4;r++) efs[rl + q*4 + r][ct*16 + l15] = f2bf(acc[r] + bias);
  }

  // msg hidden = silu(an@W1[0:128] + efs@W1[128:256] + mb1) -> hm (wave-local rows)
  bf8 ae[4];
  #pragma unroll
  for (int kt=0;kt<4;kt++)
    ae[kt] = *(const bf8*)&efs[rl + l15][kt*32 + q*8];
  #pragma unroll
  for (int ct=0; ct<8; ct++){
    f32x4 acc = {0.f,0.f,0.f,0.f};
    #pragma unroll
    for (int kt=0;kt<4;kt++){
      bf8 b = *(const bf8*)(mw1t + (ct*16 + l15)*256 + kt*32 + q*8);
      acc = __builtin_amdgcn_mfma_f32_16x16x32_bf16(an[kt], b, acc, 0,0,0);
    }
    #pragma unroll
    for (int kt=0;kt<4;kt++){
      bf8 b = *(const bf8*)(mw1t + (ct*16 + l15)*256 + 128 + kt*32 + q*8);
      acc = __builtin_amdgcn_mfma_f32_16x16x32_bf16(ae[kt], b, acc, 0,0,0);
    }
    float bias = mb1[ct*16 + l15];
    #pragma unroll
    for (int r=0;r<4;r++){
      float v = acc[r] + bias;
      v = v / (1.f + __expf(-v));
      hm[rl + q*4 + r][ct*16 + l15] = f2bf(v);
    }
  }

  // msg = hm @ mm_w2t + mb2 -> atomicAdd into agg[tgt]
  bf8 am[4];
  #pragma unroll
  for (int kt=0;kt<4;kt++) am[kt] = *(const bf8*)&hm[rl + l15][kt*32 + q*8];
  int tg[4];
  #pragma unroll
  for (int r=0;r<4;r++) tg[r] = tgts[rl + q*4 + r];
  #pragma unroll
  for (int ct=0; ct<8; ct++){
    f32x4 acc = {0.f,0.f,0.f,0.f};
    #pragma unroll
    for (int kt=0;kt<4;kt++){
      bf8 b = *(const bf8*)(mw2t + (ct*16 + l15)*HD + kt*32 + q*8);
      acc = __builtin_amdgcn_mfma_f32_16x16x32_bf16(am[kt], b, acc, 0,0,0);
    }
    float bias = mb2[ct*16 + l15];
    int col = ct*16 + l15;
    #pragma unroll
    for (int r=0;r<4;r++)
      atomicAdd(&agg[(size_t)tg[r]*HD + col], acc[r] + bias);
  }
}

// Update MLP in full fp32 (accuracy anchor)
__global__ void update_mlp_k(const float* __restrict__ agg, const float* __restrict__ cnt,
                             const float* __restrict__ w1, const float* __restrict__ b1,
                             const float* __restrict__ w2, const float* __restrict__ b2,
                             float* __restrict__ out)
{
  __shared__ float xs[32][129];
  __shared__ float hs[32][129];
  const int t = threadIdx.x;
  const int rb = blockIdx.x*32;
  {
    int e = t >> 3, c0 = (t & 7)*16;
    float c = cnt[rb + e];
    float rcp = 1.0f / fmaxf(c, 1.0f);
    const float* p = agg + (size_t)(rb + e)*HD + c0;
    #pragma unroll
    for (int i=0;i<16;i++) xs[e][c0+i] = p[i]*rcp;
  }
  __syncthreads();
  int e = t >> 3, n0 = (t & 7)*16;
  float acc[16];
  #pragma unroll
  for (int j=0;j<16;j++) acc[j] = b1[n0+j];
  for (int k=0;k<HD;k++){
    float x = xs[e][k];
    const float* wr = w1 + k*HD + n0;
    #pragma unroll
    for (int j=0;j<16;j++) acc[j] += x * wr[j];
  }
  #pragma unroll
  for (int j=0;j<16;j++){
    float v = acc[j];
    hs[e][n0+j] = v / (1.f + expf(-v));
  }
  __syncthreads();
  #pragma unroll
  for (int j=0;j<16;j++) acc[j] = b2[n0+j];
  for (int k=0;k<HD;k++){
    float x = hs[e][k];
    const float* wr = w2 + k*HD + n0;
    #pragma unroll
    for (int j=0;j<16;j++) acc[j] += x * wr[j];
  }
  float* op = out + (size_t)(rb + e)*HD + n0;
  #pragma unroll
  for (int j=0;j<16;j++) op[j] = acc[j];
}

extern "C" void kernel_launch(void* const* d_in, const int* in_sizes, int n_in,
                              void* d_out, int out_size, void* d_ws, size_t ws_size,
                              hipStream_t stream)
{
  const float* node_features = (const float*)d_in[0];
  const float* node_pos      = (const float*)d_in[1];
  const float* grid_pos      = (const float*)d_in[2];
  const int*   edge_index    = (const int*)d_in[3];
  const float* nm_w1 = (const float*)d_in[4];
  const float* nm_b1 = (const float*)d_in[5];
  const float* nm_w2 = (const float*)d_in[6];
  const float* nm_b2 = (const float*)d_in[7];
  const float* em_w1 = (const float*)d_in[8];
  const float* em_b1 = (const float*)d_in[9];
  const float* em_w2 = (const float*)d_in[10];
  const float* em_b2 = (const float*)d_in[11];
  const float* mm_w1 = (const float*)d_in[12];
  const float* mm_b1 = (const float*)d_in[13];
  const float* mm_w2 = (const float*)d_in[14];
  const float* mm_b2 = (const float*)d_in[15];
  const float* um_w1 = (const float*)d_in[16];
  const float* um_b1 = (const float*)d_in[17];
  const float* um_w2 = (const float*)d_in[18];
  const float* um_b2 = (const float*)d_in[19];
  float* out = (float*)d_out;

  char* ws = (char*)d_ws;
  short* nf  = (short*)ws;                          // 16 MB   bf16 [N,128]
  float* agg = (float*)(ws + (size_t)16777216);     // 16 MB   f32  [G,128]
  float* cnt = (float*)(ws + (size_t)33554432);     // 128 KB  f32  [G]
  short* wts = (short*)(ws + (size_t)33685504);     // ~192 KB bf16 transposed weights
  short* nmw1t = wts;
  short* nmw2t = wts + 16384;
  short* emw2t = wts + 32768;
  short* mmw1t = wts + 49152;
  short* mmw2t = wts + 81920;

  (void)hipMemsetAsync(ws + (size_t)16777216, 0, (size_t)16777216 + 131072, stream);

  prep_w_k<<<384, 256, 0, stream>>>(nm_w1, nm_w2, em_w2, mm_w1, mm_w2, wts);
  node_mlp_k<<<N_NODES/64, 256, 0, stream>>>(node_features, nmw1t, nm_b1, nmw2t, nm_b2, nf);
  edge_msg_k<<<E_EDGES/64, 256, 0, stream>>>(edge_index, node_pos, grid_pos,
      em_w1, em_b1, emw2t, em_b2, mmw1t, mm_b1, mmw2t, mm_b2, nf, agg, cnt);
  update_mlp_k<<<G_GRID/32, 256, 0, stream>>>(agg, cnt, um_w1, um_b1, um_w2, um_b2, out);
}